// Round 10
// baseline (257.837 us; speedup 1.0000x reference)
//
#include <hip/hip_runtime.h>
#include <hip/hip_bf16.h>
#include <math.h>

// Problem dims (fixed by reference)
#define BB 64
#define SS 200
#define TT 32
#define EE 128
#define CC 128
#define HH 100
#define G3 300           // 3*H
#define OUTD 104
#define NTREE (BB*SS)    // 12800

typedef __attribute__((ext_vector_type(4))) float f32x4;
typedef _Float16 f16x8 __attribute__((ext_vector_type(8)));

__device__ inline float fast_sigmoid(float x) {
    return __builtin_amdgcn_rcpf(1.f + __builtin_amdgcn_exp2f(-1.4426950408889634f * x));
}
__device__ inline float fast_tanh(float x) {
    return 1.f - 2.f * __builtin_amdgcn_rcpf(1.f + __builtin_amdgcn_exp2f(2.8853900817779268f * x));
}
__device__ inline unsigned pack2f16(float a, float b) {
    union { _Float16 h[2]; unsigned u; } x;
    x.h[0] = (_Float16)a; x.h[1] = (_Float16)b;
    return x.u;
}
// subtree size of node p in the 32-node complete binary tree
__device__ inline float subtree_cnt(int p) {
    return (p == 0) ? 32.f : (p == 1) ? 16.f : (p == 2) ? 15.f :
           (p == 3) ? 8.f  : (p <= 6) ? 7.f  : (p == 7) ? 4.f  :
           (p <= 14) ? 3.f : (p == 15) ? 2.f : 1.f;
}

// LDS-only barrier: waits ds-ops (lgkmcnt) but does NOT drain vmcnt, so in-flight
// global prefetch loads stay outstanding across the barrier (waited at use).
#define BAR() asm volatile("s_waitcnt lgkmcnt(0)\n\ts_barrier" ::: "memory")

// Workspace byte offsets:
//   wl   @ 0        : 32768 B   (k1 W_lin fragment image, fp16)
//   k2b  @ 32768    : 163840 B  (k2 W_ih fragment image, fp16)
//   thi  @ 196608   : 3276800 B (tree_vec, fp16)
//   gx   @ 3473408  : 30720000 B (fp32)
//   pool @ 0        : 51200 B   -- aliases wl/k2b; k3 writes it AFTER k1/k2 read them.

// ---------------- K0: build weight-fragment images (runs every launch; idempotent)
__global__ __launch_bounds__(256) void k0_prep(const float* __restrict__ w_lin,
                                               const float* __restrict__ w_ih_f,
                                               const float* __restrict__ w_ih_b,
                                               _Float16* __restrict__ wl,
                                               _Float16* __restrict__ k2b) {
    const int tid  = threadIdx.x;
    const int wave = tid >> 6;
    const int lane = tid & 63;
    const int r = lane & 15;
    const int q = lane >> 4;
    if (blockIdx.x == 0) {
        // k1 image: flat idx (w8 = wave*2+nt, kt, lane) -> W_lin[n=w8*16+r][k=kt*32+q*8 ..+8]
#pragma unroll
        for (int nt = 0; nt < 2; ++nt)
#pragma unroll
            for (int kt = 0; kt < 4; ++kt) {
                const int n = wave * 32 + nt * 16 + r;
                const float* src = w_lin + (long)n * EE + kt * 32 + q * 8;
                f16x8 f;
#pragma unroll
                for (int e = 0; e < 8; ++e) f[e] = (_Float16)src[e];
                *(f16x8*)&wl[(size_t)((((wave * 2 + nt) * 4 + kt) * 64) + lane) * 8] = f;
            }
    } else {
        // k2 image: nb, wave w, lane(r,q), kt -> W_ih[padded n = nb*64+w*16+r][k=kt*32+q*8]
        const int nb = blockIdx.x - 1;           // 0..9
        const int n = nb * 64 + wave * 16 + r;
        const int dir = (n >= 320) ? 1 : 0;
        const int j = n - dir * 320;
        const int jj = (j < G3) ? j : 0;         // pad rows clamped (results discarded)
        const float* w = dir ? w_ih_b : w_ih_f;
#pragma unroll
        for (int kt = 0; kt < 4; ++kt) {
            const float* src = w + (long)jj * EE + kt * 32 + q * 8;
            f16x8 f;
#pragma unroll
            for (int e = 0; e < 8; ++e) f[e] = (_Float16)src[e];
            *(f16x8*)&k2b[(size_t)((((nb * 4 + wave) * 4 + kt) * 64) + lane) * 8] = f;
        }
    }
}

// ---------------- K1 v3b: embed-gather -> MFMA1 (c = W.e) -> bpermute redistribution
// (both-tile fetch + dest-side select: bpermute src operand is evaluated on the
// SOURCE lane, so the tile index must not depend on the dest's q) -> MFMA2
// (h = L.c, L = subtree 0/1 matrix) -> in-register max + shfl -> store.
#define LDA 136                  // fp16/row: 128 + 8 pad
__global__ __launch_bounds__(512, 4) void k1_mfma(const int* __restrict__ tok,
                                                  const float* __restrict__ emb,
                                                  const _Float16* __restrict__ wl,
                                                  const float* __restrict__ b_lin,
                                                  _Float16* __restrict__ thi) {
    __shared__ __align__(16) _Float16 A_sh[64 * LDA];   // 17408 B
    __shared__ int tok_sh[64];

    const int tid  = threadIdx.x;
    const int wave = tid >> 6;      // 0..7, owns cols [16w, 16w+16)
    const int lane = tid & 63;
    const int r = lane & 15;
    const int q = lane >> 4;

    // ---- B fragments (W_lin) from prebuilt image: 4 coalesced 16B loads
    f16x8 bfrag[4];
#pragma unroll
    for (int kt = 0; kt < 4; ++kt)
        bfrag[kt] = *(const f16x8*)&wl[(size_t)(((wave * 4 + kt) * 64) + lane) * 8];
    const float bias = b_lin[wave * 16 + r];

    // ---- L-matrix A-fragments for MFMA2: L[p][n] = (n in subtree(p)), built in VALU
    f16x8 l2f[2];
#pragma unroll
    for (int mt2 = 0; mt2 < 2; ++mt2) {
        const int p = mt2 * 16 + r;
#pragma unroll
        for (int e = 0; e < 8; ++e) {
            int x = q * 8 + e;
            while (x > p) x = (x - 1) >> 1;     // walk to ancestor at/below p
            l2f[mt2][e] = (_Float16)((x == p) ? 1.f : 0.f);
        }
    }

    const int tree0 = blockIdx.x * 2;
    if (tid < 64) tok_sh[tid] = tok[tree0 * TT + tid];
    __syncthreads();

    // ---- gather embeddings -> fp16 LDS: 2 iters x (2 float4 loads + 1 b128 write)
#pragma unroll
    for (int i = 0; i < 2; ++i) {
        const int idx = tid + i * 512;          // 0..1023
        const int row = idx >> 4;               // node row 0..63
        const int p4  = idx & 15;               // 16B fp16 chunk (8 floats)
        const float4* src = (const float4*)(emb + (long)tok_sh[row] * EE + p4 * 8);
        const float4 e0 = src[0], e1 = src[1];
        f16x8 v;
        v[0] = (_Float16)e0.x; v[1] = (_Float16)e0.y; v[2] = (_Float16)e0.z; v[3] = (_Float16)e0.w;
        v[4] = (_Float16)e1.x; v[5] = (_Float16)e1.y; v[6] = (_Float16)e1.z; v[7] = (_Float16)e1.w;
        *(f16x8*)&A_sh[row * LDA + p4 * 8] = v;
    }
    __syncthreads();   // only barrier in k1

    // ---- MFMA1: C1[64 nodes][16 cols] per wave; pack each (mt) tile to fp16 pairs
    unsigned pk[4][2];    // pk[mt][pair]: pair0 = regs(0,1), pair1 = regs(2,3)
#pragma unroll
    for (int mt = 0; mt < 4; ++mt) {
        const int m = mt * 16 + r;
        f32x4 acc = (f32x4)(0.f);
#pragma unroll
        for (int kt = 0; kt < 4; ++kt) {
            f16x8 af = *(const f16x8*)&A_sh[m * LDA + kt * 32 + q * 8];
            acc = __builtin_amdgcn_mfma_f32_16x16x32_f16(af, bfrag[kt], acc, 0, 0, 0);
        }
        pk[mt][0] = pack2f16(acc[0], acc[1]);
        pk[mt][1] = pack2f16(acc[2], acc[3]);
    }

    // ---- per tree: wave-local bpermute -> B2 frag -> MFMA2 -> max epilogue
    // B2[k=node][n=col]: lane(r,q) elem e = C1[node=q*8+e][col=r]. Source lane
    // r+16*q_src with q_src=((2q+(e>>2))&3), tile = 2t+(q>>1), reg = e&3.
    // The tile index depends on the DEST's q, but bpermute's src operand is read
    // on the SOURCE lane -> fetch both tiles, select locally by hi=(q>>1).
#pragma unroll
    for (int t = 0; t < 2; ++t) {
        const int l0 = (r + 16 * ((2 * q) & 3)) << 2;
        const int l1 = (r + 16 * ((2 * q + 1) & 3)) << 2;
        const bool hi = (q >> 1) != 0;
        const unsigned x0 = __builtin_amdgcn_ds_bpermute(l0, (int)pk[2 * t][0]);
        const unsigned y0 = __builtin_amdgcn_ds_bpermute(l0, (int)pk[2 * t + 1][0]);
        const unsigned x1 = __builtin_amdgcn_ds_bpermute(l0, (int)pk[2 * t][1]);
        const unsigned y1 = __builtin_amdgcn_ds_bpermute(l0, (int)pk[2 * t + 1][1]);
        const unsigned x2 = __builtin_amdgcn_ds_bpermute(l1, (int)pk[2 * t][0]);
        const unsigned y2 = __builtin_amdgcn_ds_bpermute(l1, (int)pk[2 * t + 1][0]);
        const unsigned x3 = __builtin_amdgcn_ds_bpermute(l1, (int)pk[2 * t][1]);
        const unsigned y3 = __builtin_amdgcn_ds_bpermute(l1, (int)pk[2 * t + 1][1]);
        union { unsigned u[4]; f16x8 v; } b2;
        b2.u[0] = hi ? y0 : x0;
        b2.u[1] = hi ? y1 : x1;
        b2.u[2] = hi ? y2 : x2;
        b2.u[3] = hi ? y3 : x3;

        float mx = -1e30f;
#pragma unroll
        for (int mt2 = 0; mt2 < 2; ++mt2) {
            f32x4 a2 = __builtin_amdgcn_mfma_f32_16x16x32_f16(l2f[mt2], b2.v, (f32x4)(0.f), 0, 0, 0);
#pragma unroll
            for (int reg = 0; reg < 4; ++reg) {
                const int p = mt2 * 16 + q * 4 + reg;       // h(p) = C2 + cnt(p)*bias
                mx = fmaxf(mx, a2[reg] + subtree_cnt(p) * bias);
            }
        }
        mx = fmaxf(mx, __shfl_xor(mx, 16, 64));
        mx = fmaxf(mx, __shfl_xor(mx, 32, 64));
        if (q == 0)
            thi[(size_t)(tree0 + t) * CC + wave * 16 + r] = (_Float16)mx;
    }
}

// ---------------- K2 (fp16 MFMA): gx[dir][m=b*S+s][300] = X @ W_ih^T + b_ih
__global__ __launch_bounds__(256) void k2_mfma(const _Float16* __restrict__ thi,
                                               const _Float16* __restrict__ k2b,
                                               const float* __restrict__ b_ih_f,
                                               const float* __restrict__ b_ih_b,
                                               float* __restrict__ gx) {
    __shared__ __align__(16) _Float16 Ah[32 * LDA];   // 8704 B

    const int tid  = threadIdx.x;
    const int wave = tid >> 6;
    const int lane = tid & 63;
    const int r = lane & 15;
    const int q = lane >> 4;

    const int nb = blockIdx.x % 10;
    const int mb = blockIdx.x / 10;
    const int m0 = mb * 32;
    const int n0 = nb * 64;

#pragma unroll
    for (int i = 0; i < 2; ++i) {
        const int idx = tid + i * 256;
        const int row = idx >> 4;
        const int p   = idx & 15;
        f16x8 v = *(const f16x8*)&thi[(size_t)(m0 + row) * CC + p * 8];
        *(f16x8*)&Ah[row * LDA + p * 8] = v;
    }
    f16x8 bh[4];
#pragma unroll
    for (int kt = 0; kt < 4; ++kt)
        bh[kt] = *(const f16x8*)&k2b[(size_t)((((nb * 4 + wave) * 4 + kt) * 64) + lane) * 8];
    __syncthreads();

    f32x4 acc[2];
    acc[0] = (f32x4)(0.f); acc[1] = (f32x4)(0.f);
#pragma unroll
    for (int mt = 0; mt < 2; ++mt) {
        const int m = mt * 16 + r;
#pragma unroll
        for (int kt = 0; kt < 4; ++kt) {
            f16x8 a = *(const f16x8*)&Ah[m * LDA + kt * 32 + q * 8];
            acc[mt] = __builtin_amdgcn_mfma_f32_16x16x32_f16(a, bh[kt], acc[mt], 0, 0, 0);
        }
    }

    const int ng  = n0 + wave * 16 + r;
    const int dir = (ng >= 320) ? 1 : 0;
    const int j   = ng - dir * 320;
    const bool valid = (j < G3);
    const float bias = valid ? (dir ? b_ih_b[j] : b_ih_f[j]) : 0.f;
    float* gxd = gx + (long)dir * NTREE * G3;
    if (valid) {
#pragma unroll
        for (int mt = 0; mt < 2; ++mt)
#pragma unroll
            for (int reg = 0; reg < 4; ++reg) {
                const int m = m0 + mt * 16 + q * 4 + reg;
                gxd[(long)m * G3 + j] = acc[mt][reg] + bias;
            }
    }
}

// ---------------- K3 v5 (unchanged, measured 100.8 us): 1 chain/block, fp16 MFMA matvec,
// row-permuted W_hh (wave-local gates), one lgkm-only barrier/step, h double-buffered.
__global__ __launch_bounds__(256, 1) void k3_gru(const float* __restrict__ gx,
                                                 const float* __restrict__ w_hh_f,
                                                 const float* __restrict__ b_hh_f,
                                                 const float* __restrict__ w_hh_b,
                                                 const float* __restrict__ b_hh_b,
                                                 float* __restrict__ pool) {
    const int bid = blockIdx.x;   // 0..127
    const int dir = bid & 1;
    const int b = bid >> 1;
    const float* w_hh = dir ? w_hh_b : w_hh_f;
    const float* b_hh = dir ? b_hh_b : b_hh_f;

    __shared__ __align__(16) _Float16 h_sh[2][128];
    __shared__ float g_sh[4][80];

    const int tid  = threadIdx.x;
    const int wave = tid >> 6;
    const int lane = tid & 63;
    const int r = lane & 15;
    const int q = lane >> 4;

    f16x8 bf[5][4];
#pragma unroll
    for (int i = 0; i < 5; ++i) {
        const int l = i * 16 + r;
        const int gate = l / 25;
        const int ch   = l - gate * 25;
        const bool nv  = (l < 75);
        const int row  = gate * HH + wave * 25 + ch;
#pragma unroll
        for (int kt = 0; kt < 4; ++kt) {
            f16x8 f;
#pragma unroll
            for (int e = 0; e < 8; ++e) {
                const int k = kt * 32 + q * 8 + e;
                f[e] = (_Float16)((nv && k < HH) ? w_hh[row * HH + k] : 0.f);
            }
            bf[i][kt] = f;
        }
    }

    const int m = lane;
    const int c = wave * 25 + m;
    const bool act = (m < 25);
    float br = 0.f, bz = 0.f, bn = 0.f;
    if (act) { br = b_hh[c]; bz = b_hh[HH + c]; bn = b_hh[2 * HH + c]; }

    if (tid < 128) { h_sh[0][tid] = (_Float16)0.f; h_sh[1][tid] = (_Float16)0.f; }

    const float* gxd = gx + (long)dir * NTREE * G3;
    const int sstep = dir ? -1 : 1;
    int s = dir ? (SS - 1) : 0;
    float xr = 0.f, xz = 0.f, xn = 0.f;
    if (act) {
        const float* row0 = gxd + ((long)b * SS + s) * G3;
        xr = row0[c]; xz = row0[HH + c]; xn = row0[2 * HH + c];
    }
    float hj = 0.f, hmax = -1e30f;
    __syncthreads();

    for (int t = 0; t < SS; ++t) {
        const int p = t & 1;
        const int s_n = s + sstep;
        float xrn = 0.f, xzn = 0.f, xnn = 0.f;
        if (act && t < SS - 1) {
            const float* row0 = gxd + ((long)b * SS + s_n) * G3;
            xrn = row0[c]; xzn = row0[HH + c]; xnn = row0[2 * HH + c];
        }

        f16x8 a[4];
#pragma unroll
        for (int kt = 0; kt < 4; ++kt)
            a[kt] = *(const f16x8*)&h_sh[p][kt * 32 + q * 8];
        f32x4 acc[5];
#pragma unroll
        for (int i = 0; i < 5; ++i) {
            acc[i] = (f32x4)(0.f);
#pragma unroll
            for (int kt = 0; kt < 4; ++kt)
                acc[i] = __builtin_amdgcn_mfma_f32_16x16x32_f16(a[kt], bf[i][kt], acc[i], 0, 0, 0);
        }
        if (q == 0) {
#pragma unroll
            for (int i = 0; i < 5; ++i)
                g_sh[wave][i * 16 + r] = acc[i][0];
        }
        if (act) {
            const float ghr = g_sh[wave][m];
            const float ghz = g_sh[wave][25 + m];
            const float ghn = g_sh[wave][50 + m];
            const float rg = fast_sigmoid(xr + ghr + br);
            const float zg = fast_sigmoid(xz + ghz + bz);
            const float ng = fast_tanh(xn + rg * (ghn + bn));
            hj = (1.f - zg) * ng + zg * hj;
            hmax = fmaxf(hmax, hj);
            h_sh[1 - p][c] = (_Float16)hj;
            xr = xrn; xz = xzn; xn = xnn;
        }
        BAR();
        s = s_n;
    }
    if (act) pool[(long)b * (2 * HH) + dir * HH + c] = hmax;
}

// ---------------- K4: out[b][o] = fc_b[o] + pool[b,:] . fc_w[o,:]
__global__ __launch_bounds__(256) void k4_fc(const float* __restrict__ pool,
                                             const float* __restrict__ fc_w,
                                             const float* __restrict__ fc_b,
                                             float* __restrict__ out) {
    const int b = blockIdx.x;
    __shared__ __align__(16) float p_sh[2 * HH];
    const int t = threadIdx.x;
    if (t < 2 * HH) p_sh[t] = pool[(long)b * (2 * HH) + t];
    __syncthreads();
    if (t < OUTD) {
        const float4* wr4 = (const float4*)(fc_w + (long)t * (2 * HH));
        const float4* p4 = (const float4*)p_sh;
        float a0 = 0.f, a1 = 0.f;
#pragma unroll
        for (int k = 0; k < 50; k += 2) {
            float4 w0 = wr4[k],   p0 = p4[k];
            float4 w1 = wr4[k+1], p1 = p4[k+1];
            a0 += w0.x*p0.x + w0.y*p0.y + w0.z*p0.z + w0.w*p0.w;
            a1 += w1.x*p1.x + w1.y*p1.y + w1.z*p1.z + w1.w*p1.w;
        }
        out[(long)b * OUTD + t] = fc_b[t] + a0 + a1;
    }
}

extern "C" void kernel_launch(void* const* d_in, const int* in_sizes, int n_in,
                              void* d_out, int out_size, void* d_ws, size_t ws_size,
                              hipStream_t stream) {
    const int*   tok    = (const int*)d_in[0];
    const float* emb    = (const float*)d_in[4];
    const float* w_lin  = (const float*)d_in[5];
    const float* b_lin  = (const float*)d_in[6];
    const float* w_ih_f = (const float*)d_in[7];
    const float* w_hh_f = (const float*)d_in[8];
    const float* b_ih_f = (const float*)d_in[9];
    const float* b_hh_f = (const float*)d_in[10];
    const float* w_ih_b = (const float*)d_in[11];
    const float* w_hh_b = (const float*)d_in[12];
    const float* b_ih_b = (const float*)d_in[13];
    const float* b_hh_b = (const float*)d_in[14];
    const float* fc_w   = (const float*)d_in[15];
    const float* fc_b   = (const float*)d_in[16];

    char* wsb = (char*)d_ws;
    _Float16* wl   = (_Float16*)(wsb);             // 32768 B
    _Float16* k2b  = (_Float16*)(wsb + 32768);     // 163840 B
    _Float16* thi  = (_Float16*)(wsb + 196608);    // 3276800 B
    float*    gx   = (float*)(wsb + 3473408);      // 30720000 B
    float*    pool = (float*)(wsb);                // aliases wl/k2b: k3 runs after k1/k2
    float*    out  = (float*)d_out;

    k0_prep<<<11, 256, 0, stream>>>(w_lin, w_ih_f, w_ih_b, wl, k2b);
    k1_mfma<<<NTREE / 2, 512, 0, stream>>>(tok, emb, wl, b_lin, thi);
    k2_mfma<<<(NTREE / 32) * 10, 256, 0, stream>>>(thi, k2b, b_ih_f, b_ih_b, gx);
    k3_gru <<<2 * BB, 256, 0, stream>>>(gx, w_hh_f, b_hh_f, w_hh_b, b_hh_b, pool);
    k4_fc  <<<BB, 256, 0, stream>>>(pool, fc_w, fc_b, out);
}

// Round 11
// 252.924 us; speedup vs baseline: 1.0194x; 1.0194x over previous
//
#include <hip/hip_runtime.h>
#include <hip/hip_bf16.h>
#include <math.h>

// Problem dims (fixed by reference)
#define BB 64
#define SS 200
#define TT 32
#define EE 128
#define CC 128
#define HH 100
#define G3 300           // 3*H
#define OUTD 104
#define NTREE (BB*SS)    // 12800
#define EMB_N (50000 * EE)   // 6,400,000 elements

typedef __attribute__((ext_vector_type(4))) float f32x4;
typedef _Float16 f16x8 __attribute__((ext_vector_type(8)));

__device__ inline float fast_sigmoid(float x) {
    return __builtin_amdgcn_rcpf(1.f + __builtin_amdgcn_exp2f(-1.4426950408889634f * x));
}
__device__ inline float fast_tanh(float x) {
    return 1.f - 2.f * __builtin_amdgcn_rcpf(1.f + __builtin_amdgcn_exp2f(2.8853900817779268f * x));
}
__device__ inline unsigned pack2f16(float a, float b) {
    union { _Float16 h[2]; unsigned u; } x;
    x.h[0] = (_Float16)a; x.h[1] = (_Float16)b;
    return x.u;
}
__device__ inline unsigned f2u(float v) { union { float f; unsigned u; } x; x.f = v; return x.u; }
__device__ inline float u2f(unsigned v) { union { unsigned u; float f; } x; x.u = v; return x.f; }
// subtree size of node p in the 32-node complete binary tree
__device__ inline float subtree_cnt(int p) {
    return (p == 0) ? 32.f : (p == 1) ? 16.f : (p == 2) ? 15.f :
           (p == 3) ? 8.f  : (p <= 6) ? 7.f  : (p == 7) ? 4.f  :
           (p <= 14) ? 3.f : (p == 15) ? 2.f : 1.f;
}

// LDS-only barrier: waits ds-ops (lgkmcnt) but does NOT drain vmcnt, so in-flight
// global prefetch loads stay outstanding across the barrier (waited at use).
#define BAR() asm volatile("s_waitcnt lgkmcnt(0)\n\ts_barrier" ::: "memory")

// Workspace byte offsets:
//   wl    @ 0        : 32768 B    (k1 W_lin fragment image, fp16)
//   k2b   @ 32768    : 163840 B   (k2 W_ih fragment image, fp16)
//   thi   @ 196608   : 3276800 B  (tree_vec, fp16)
//   gx    @ 3473408  : 30720000 B (fp32)   -- ALSO holds emb16 (12.8 MB) during k0/k1;
//                                             k2 overwrites it after k1 is done (stream order).
//   pool  @ 0        : 51200 B    -- aliases wl/k2b; k3 writes AFTER k1/k2 read them.

// ---------------- K0: weight-fragment images + fp16 embedding table (idempotent)
__global__ __launch_bounds__(256) void k0_prep(const float* __restrict__ w_lin,
                                               const float* __restrict__ w_ih_f,
                                               const float* __restrict__ w_ih_b,
                                               const float* __restrict__ emb,
                                               _Float16* __restrict__ wl,
                                               _Float16* __restrict__ k2b,
                                               _Float16* __restrict__ emb16) {
    const int tid  = threadIdx.x;
    const int wave = tid >> 6;
    const int lane = tid & 63;
    const int r = lane & 15;
    const int q = lane >> 4;
    if (blockIdx.x == 0) {
        // k1 image: flat idx (w8 = wave*2+nt, kt, lane) -> W_lin[n=w8*16+r][k=kt*32+q*8 ..+8]
#pragma unroll
        for (int nt = 0; nt < 2; ++nt)
#pragma unroll
            for (int kt = 0; kt < 4; ++kt) {
                const int n = wave * 32 + nt * 16 + r;
                const float* src = w_lin + (long)n * EE + kt * 32 + q * 8;
                f16x8 f;
#pragma unroll
                for (int e = 0; e < 8; ++e) f[e] = (_Float16)src[e];
                *(f16x8*)&wl[(size_t)((((wave * 2 + nt) * 4 + kt) * 64) + lane) * 8] = f;
            }
    } else if (blockIdx.x <= 10) {
        // k2 image: nb, wave w, lane(r,q), kt -> W_ih[padded n = nb*64+w*16+r][k=kt*32+q*8]
        const int nb = blockIdx.x - 1;           // 0..9
        const int n = nb * 64 + wave * 16 + r;
        const int dir = (n >= 320) ? 1 : 0;
        const int j = n - dir * 320;
        const int jj = (j < G3) ? j : 0;         // pad rows clamped (results discarded)
        const float* w = dir ? w_ih_b : w_ih_f;
#pragma unroll
        for (int kt = 0; kt < 4; ++kt) {
            const float* src = w + (long)jj * EE + kt * 32 + q * 8;
            f16x8 f;
#pragma unroll
            for (int e = 0; e < 8; ++e) f[e] = (_Float16)src[e];
            *(f16x8*)&k2b[(size_t)((((nb * 4 + wave) * 4 + kt) * 64) + lane) * 8] = f;
        }
    } else {
        // fp16 embedding table: blocks 11.. convert 8192 elements each (streaming)
        const long base = (long)(blockIdx.x - 11) * 8192;
#pragma unroll
        for (int i = 0; i < 4; ++i) {
            const long off = base + i * 2048 + tid * 8;
            if (off < EMB_N) {
                const float4 e0 = ((const float4*)(emb + off))[0];
                const float4 e1 = ((const float4*)(emb + off))[1];
                f16x8 v;
                v[0] = (_Float16)e0.x; v[1] = (_Float16)e0.y; v[2] = (_Float16)e0.z; v[3] = (_Float16)e0.w;
                v[4] = (_Float16)e1.x; v[5] = (_Float16)e1.y; v[6] = (_Float16)e1.z; v[7] = (_Float16)e1.w;
                *(f16x8*)&emb16[off] = v;
            }
        }
    }
}

// ---------------- K1: fp16-gather -> MFMA1 (c = W.e) -> bpermute redistribution
// -> MFMA2 (h = L.c, L = subtree 0/1 matrix) -> in-register max + shfl -> store.
#define LDA 136                  // fp16/row: 128 + 8 pad
__global__ __launch_bounds__(512, 4) void k1_mfma(const int* __restrict__ tok,
                                                  const _Float16* __restrict__ emb16,
                                                  const _Float16* __restrict__ wl,
                                                  const float* __restrict__ b_lin,
                                                  _Float16* __restrict__ thi) {
    __shared__ __align__(16) _Float16 A_sh[64 * LDA];   // 17408 B
    __shared__ int tok_sh[64];

    const int tid  = threadIdx.x;
    const int wave = tid >> 6;      // 0..7, owns cols [16w, 16w+16)
    const int lane = tid & 63;
    const int r = lane & 15;
    const int q = lane >> 4;

    // ---- B fragments (W_lin) from prebuilt image: 4 coalesced 16B loads
    f16x8 bfrag[4];
#pragma unroll
    for (int kt = 0; kt < 4; ++kt)
        bfrag[kt] = *(const f16x8*)&wl[(size_t)(((wave * 4 + kt) * 64) + lane) * 8];
    const float bias = b_lin[wave * 16 + r];

    // ---- L-matrix A-fragments for MFMA2: L[p][n] = (n in subtree(p)), built in VALU
    f16x8 l2f[2];
#pragma unroll
    for (int mt2 = 0; mt2 < 2; ++mt2) {
        const int p = mt2 * 16 + r;
#pragma unroll
        for (int e = 0; e < 8; ++e) {
            int x = q * 8 + e;
            while (x > p) x = (x - 1) >> 1;     // walk to ancestor at/below p
            l2f[mt2][e] = (_Float16)((x == p) ? 1.f : 0.f);
        }
    }

    const int tree0 = blockIdx.x * 2;
    if (tid < 64) tok_sh[tid] = tok[tree0 * TT + tid];
    __syncthreads();

    // ---- gather fp16 embeddings -> LDS (copy-only; 256 B/row, coalesced per row)
#pragma unroll
    for (int i = 0; i < 2; ++i) {
        const int idx = tid + i * 512;          // 0..1023
        const int row = idx >> 4;               // node row 0..63
        const int p4  = idx & 15;               // 16B chunk
        f16x8 v = *(const f16x8*)&emb16[(size_t)tok_sh[row] * EE + p4 * 8];
        *(f16x8*)&A_sh[row * LDA + p4 * 8] = v;
    }
    __syncthreads();   // only barrier in k1

    // ---- MFMA1: C1[64 nodes][16 cols] per wave; pack each (mt) tile to fp16 pairs
    unsigned pk[4][2];    // pk[mt][pair]: pair0 = regs(0,1), pair1 = regs(2,3)
#pragma unroll
    for (int mt = 0; mt < 4; ++mt) {
        const int m = mt * 16 + r;
        f32x4 acc = (f32x4)(0.f);
#pragma unroll
        for (int kt = 0; kt < 4; ++kt) {
            f16x8 af = *(const f16x8*)&A_sh[m * LDA + kt * 32 + q * 8];
            acc = __builtin_amdgcn_mfma_f32_16x16x32_f16(af, bfrag[kt], acc, 0, 0, 0);
        }
        pk[mt][0] = pack2f16(acc[0], acc[1]);
        pk[mt][1] = pack2f16(acc[2], acc[3]);
    }

    // ---- per tree: wave-local bpermute (both-tile fetch + dest-side select; the
    // bpermute src operand is evaluated on the SOURCE lane) -> MFMA2 -> max epilogue
#pragma unroll
    for (int t = 0; t < 2; ++t) {
        const int l0 = (r + 16 * ((2 * q) & 3)) << 2;
        const int l1 = (r + 16 * ((2 * q + 1) & 3)) << 2;
        const bool hi = (q >> 1) != 0;
        const unsigned x0 = __builtin_amdgcn_ds_bpermute(l0, (int)pk[2 * t][0]);
        const unsigned y0 = __builtin_amdgcn_ds_bpermute(l0, (int)pk[2 * t + 1][0]);
        const unsigned x1 = __builtin_amdgcn_ds_bpermute(l0, (int)pk[2 * t][1]);
        const unsigned y1 = __builtin_amdgcn_ds_bpermute(l0, (int)pk[2 * t + 1][1]);
        const unsigned x2 = __builtin_amdgcn_ds_bpermute(l1, (int)pk[2 * t][0]);
        const unsigned y2 = __builtin_amdgcn_ds_bpermute(l1, (int)pk[2 * t + 1][0]);
        const unsigned x3 = __builtin_amdgcn_ds_bpermute(l1, (int)pk[2 * t][1]);
        const unsigned y3 = __builtin_amdgcn_ds_bpermute(l1, (int)pk[2 * t + 1][1]);
        union { unsigned u[4]; f16x8 v; } b2;
        b2.u[0] = hi ? y0 : x0;
        b2.u[1] = hi ? y1 : x1;
        b2.u[2] = hi ? y2 : x2;
        b2.u[3] = hi ? y3 : x3;

        float mx = -1e30f;
#pragma unroll
        for (int mt2 = 0; mt2 < 2; ++mt2) {
            f32x4 a2 = __builtin_amdgcn_mfma_f32_16x16x32_f16(l2f[mt2], b2.v, (f32x4)(0.f), 0, 0, 0);
#pragma unroll
            for (int reg = 0; reg < 4; ++reg) {
                const int p = mt2 * 16 + q * 4 + reg;       // h(p) = C2 + cnt(p)*bias
                mx = fmaxf(mx, a2[reg] + subtree_cnt(p) * bias);
            }
        }
        mx = fmaxf(mx, __shfl_xor(mx, 16, 64));
        mx = fmaxf(mx, __shfl_xor(mx, 32, 64));
        if (q == 0)
            thi[(size_t)(tree0 + t) * CC + wave * 16 + r] = (_Float16)mx;
    }
}

// ---------------- K2 (fp16 MFMA): gx[dir][m=b*S+s][300] = X @ W_ih^T + b_ih
__global__ __launch_bounds__(256) void k2_mfma(const _Float16* __restrict__ thi,
                                               const _Float16* __restrict__ k2b,
                                               const float* __restrict__ b_ih_f,
                                               const float* __restrict__ b_ih_b,
                                               float* __restrict__ gx) {
    __shared__ __align__(16) _Float16 Ah[32 * LDA];   // 8704 B

    const int tid  = threadIdx.x;
    const int wave = tid >> 6;
    const int lane = tid & 63;
    const int r = lane & 15;
    const int q = lane >> 4;

    const int nb = blockIdx.x % 10;
    const int mb = blockIdx.x / 10;
    const int m0 = mb * 32;
    const int n0 = nb * 64;

#pragma unroll
    for (int i = 0; i < 2; ++i) {
        const int idx = tid + i * 256;
        const int row = idx >> 4;
        const int p   = idx & 15;
        f16x8 v = *(const f16x8*)&thi[(size_t)(m0 + row) * CC + p * 8];
        *(f16x8*)&Ah[row * LDA + p * 8] = v;
    }
    f16x8 bh[4];
#pragma unroll
    for (int kt = 0; kt < 4; ++kt)
        bh[kt] = *(const f16x8*)&k2b[(size_t)((((nb * 4 + wave) * 4 + kt) * 64) + lane) * 8];
    __syncthreads();

    f32x4 acc[2];
    acc[0] = (f32x4)(0.f); acc[1] = (f32x4)(0.f);
#pragma unroll
    for (int mt = 0; mt < 2; ++mt) {
        const int m = mt * 16 + r;
#pragma unroll
        for (int kt = 0; kt < 4; ++kt) {
            f16x8 a = *(const f16x8*)&Ah[m * LDA + kt * 32 + q * 8];
            acc[mt] = __builtin_amdgcn_mfma_f32_16x16x32_f16(a, bh[kt], acc[mt], 0, 0, 0);
        }
    }

    const int ng  = n0 + wave * 16 + r;
    const int dir = (ng >= 320) ? 1 : 0;
    const int j   = ng - dir * 320;
    const bool valid = (j < G3);
    const float bias = valid ? (dir ? b_ih_b[j] : b_ih_f[j]) : 0.f;
    float* gxd = gx + (long)dir * NTREE * G3;
    if (valid) {
#pragma unroll
        for (int mt = 0; mt < 2; ++mt)
#pragma unroll
            for (int reg = 0; reg < 4; ++reg) {
                const int m = m0 + mt * 16 + q * 4 + reg;
                gxd[(long)m * G3 + j] = acc[mt][reg] + bias;
            }
    }
}

// ---------------- K3 v6: 1 chain/block (128 blocks, 4 waves), fp16 MFMA matvec.
// Changes vs v5 (measured 1212 cyc/step): (1) gates leave the MFMA via wave-local
// ds_bpermute + own-register selects (ALL C rows are identical since A is the
// broadcast h, so every lane holds g[i*16+r] in acc[i]) -- removes the g_sh LDS
// store->load round trip; (2) 2+2 split MFMA chains halve dependency latency.
__global__ __launch_bounds__(256, 1) void k3_gru(const float* __restrict__ gx,
                                                 const float* __restrict__ w_hh_f,
                                                 const float* __restrict__ b_hh_f,
                                                 const float* __restrict__ w_hh_b,
                                                 const float* __restrict__ b_hh_b,
                                                 float* __restrict__ pool) {
    const int bid = blockIdx.x;   // 0..127
    const int dir = bid & 1;
    const int b = bid >> 1;
    const float* w_hh = dir ? w_hh_b : w_hh_f;
    const float* b_hh = dir ? b_hh_b : b_hh_f;

    __shared__ __align__(16) _Float16 h_sh[2][128];   // double-buffered h (k-pad 0)

    const int tid  = threadIdx.x;
    const int wave = tid >> 6;
    const int lane = tid & 63;
    const int r = lane & 15;
    const int q = lane >> 4;

    // ---- persistent B fragments (fp16), PERMUTED rows: wave w owns channels
    // [25w, 25w+25). Local row l = i*16+r: l<25 -> gate r(ch=l), l<50 -> z, l<75 -> n.
    f16x8 bf[5][4];
#pragma unroll
    for (int i = 0; i < 5; ++i) {
        const int l = i * 16 + r;
        const int gate = l / 25;
        const int ch   = l - gate * 25;
        const bool nv  = (l < 75);
        const int row  = gate * HH + wave * 25 + ch;
#pragma unroll
        for (int kt = 0; kt < 4; ++kt) {
            f16x8 f;
#pragma unroll
            for (int e = 0; e < 8; ++e) {
                const int k = kt * 32 + q * 8 + e;
                f[e] = (_Float16)((nv && k < HH) ? w_hh[row * HH + k] : 0.f);
            }
            bf[i][kt] = f;
        }
    }

    const int m = lane;              // activation lane: m<25 owns channel c = 25w+m
    const int c = wave * 25 + m;
    const bool act = (m < 25);
    float br = 0.f, bz = 0.f, bn = 0.f;
    if (act) { br = b_hh[c]; bz = b_hh[HH + c]; bn = b_hh[2 * HH + c]; }

    if (tid < 128) { h_sh[0][tid] = (_Float16)0.f; h_sh[1][tid] = (_Float16)0.f; }

    const float* gxd = gx + (long)dir * NTREE * G3;
    const int sstep = dir ? -1 : 1;
    int s = dir ? (SS - 1) : 0;
    float xr = 0.f, xz = 0.f, xn = 0.f;
    if (act) {
        const float* row0 = gxd + ((long)b * SS + s) * G3;
        xr = row0[c]; xz = row0[HH + c]; xn = row0[2 * HH + c];
    }
    float hj = 0.f, hmax = -1e30f;
    // gate-bpermute source-lane addresses (dest lane m pulls col (pos&15), q=0 lanes)
    const int lz = ((25 + m) & 15) << 2;
    const int ln = ((50 + m) & 15) << 2;
    __syncthreads();

    for (int t = 0; t < SS; ++t) {
        const int p = t & 1;
        const int s_n = s + sstep;
        // prefetch next step's gx (survives the lgkm-only barrier; waited at use)
        float xrn = 0.f, xzn = 0.f, xnn = 0.f;
        if (act && t < SS - 1) {
            const float* row0 = gxd + ((long)b * SS + s_n) * G3;
            xrn = row0[c]; xzn = row0[HH + c]; xnn = row0[2 * HH + c];
        }

        // ---- matvec: A = h broadcast to all 16 rows -> all C rows identical
        f16x8 a[4];
#pragma unroll
        for (int kt = 0; kt < 4; ++kt)
            a[kt] = *(const f16x8*)&h_sh[p][kt * 32 + q * 8];   // broadcast b128
        float g[5];
#pragma unroll
        for (int i = 0; i < 5; ++i) {
            f32x4 a0 = __builtin_amdgcn_mfma_f32_16x16x32_f16(a[0], bf[i][0], (f32x4)(0.f), 0, 0, 0);
            a0       = __builtin_amdgcn_mfma_f32_16x16x32_f16(a[1], bf[i][1], a0, 0, 0, 0);
            f32x4 a1 = __builtin_amdgcn_mfma_f32_16x16x32_f16(a[2], bf[i][2], (f32x4)(0.f), 0, 0, 0);
            a1       = __builtin_amdgcn_mfma_f32_16x16x32_f16(a[3], bf[i][3], a1, 0, 0, 0);
            g[i] = a0[0] + a1[0];     // g[i] on lane(r,q) = gate value at local row i*16+r
        }

        // ---- gate redistribution, wave-local (no LDS):
        // ghr (pos=m):    own register, tile m>>4
        // ghz (pos=25+m): tile in {1,2,3}, col (25+m)&15 -> pull from q=0 lane
        // ghn (pos=50+m): tile in {3,4},   col (50+m)&15
        const unsigned bz1 = __builtin_amdgcn_ds_bpermute(lz, (int)f2u(g[1]));
        const unsigned bz2 = __builtin_amdgcn_ds_bpermute(lz, (int)f2u(g[2]));
        const unsigned bz3 = __builtin_amdgcn_ds_bpermute(lz, (int)f2u(g[3]));
        const unsigned bn3 = __builtin_amdgcn_ds_bpermute(ln, (int)f2u(g[3]));
        const unsigned bn4 = __builtin_amdgcn_ds_bpermute(ln, (int)f2u(g[4]));

        if (act) {
            const float ghr = (m < 16) ? g[0] : g[1];
            const float ghz = (m < 7) ? u2f(bz1) : (m < 23) ? u2f(bz2) : u2f(bz3);
            const float ghn = (m < 14) ? u2f(bn3) : u2f(bn4);
            const float rg = fast_sigmoid(xr + ghr + br);
            const float zg = fast_sigmoid(xz + ghz + bz);
            const float ng = fast_tanh(xn + rg * (ghn + bn));
            hj = (1.f - zg) * ng + zg * hj;
            hmax = fmaxf(hmax, hj);
            h_sh[1 - p][c] = (_Float16)hj;   // next step's buffer
            xr = xrn; xz = xzn; xn = xnn;
        }
        BAR();   // single barrier per step: publish h to all waves
        s = s_n;
    }
    if (act) pool[(long)b * (2 * HH) + dir * HH + c] = hmax;
}

// ---------------- K4: out[b][o] = fc_b[o] + pool[b,:] . fc_w[o,:]
__global__ __launch_bounds__(256) void k4_fc(const float* __restrict__ pool,
                                             const float* __restrict__ fc_w,
                                             const float* __restrict__ fc_b,
                                             float* __restrict__ out) {
    const int b = blockIdx.x;
    __shared__ __align__(16) float p_sh[2 * HH];
    const int t = threadIdx.x;
    if (t < 2 * HH) p_sh[t] = pool[(long)b * (2 * HH) + t];
    __syncthreads();
    if (t < OUTD) {
        const float4* wr4 = (const float4*)(fc_w + (long)t * (2 * HH));
        const float4* p4 = (const float4*)p_sh;
        float a0 = 0.f, a1 = 0.f;
#pragma unroll
        for (int k = 0; k < 50; k += 2) {
            float4 w0 = wr4[k],   p0 = p4[k];
            float4 w1 = wr4[k+1], p1 = p4[k+1];
            a0 += w0.x*p0.x + w0.y*p0.y + w0.z*p0.z + w0.w*p0.w;
            a1 += w1.x*p1.x + w1.y*p1.y + w1.z*p1.z + w1.w*p1.w;
        }
        out[(long)b * OUTD + t] = fc_b[t] + a0 + a1;
    }
}

extern "C" void kernel_launch(void* const* d_in, const int* in_sizes, int n_in,
                              void* d_out, int out_size, void* d_ws, size_t ws_size,
                              hipStream_t stream) {
    const int*   tok    = (const int*)d_in[0];
    const float* emb    = (const float*)d_in[4];
    const float* w_lin  = (const float*)d_in[5];
    const float* b_lin  = (const float*)d_in[6];
    const float* w_ih_f = (const float*)d_in[7];
    const float* w_hh_f = (const float*)d_in[8];
    const float* b_ih_f = (const float*)d_in[9];
    const float* b_hh_f = (const float*)d_in[10];
    const float* w_ih_b = (const float*)d_in[11];
    const float* w_hh_b = (const float*)d_in[12];
    const float* b_ih_b = (const float*)d_in[13];
    const float* b_hh_b = (const float*)d_in[14];
    const float* fc_w   = (const float*)d_in[15];
    const float* fc_b   = (const float*)d_in[16];

    char* wsb = (char*)d_ws;
    _Float16* wl    = (_Float16*)(wsb);             // 32768 B
    _Float16* k2b   = (_Float16*)(wsb + 32768);     // 163840 B
    _Float16* thi   = (_Float16*)(wsb + 196608);    // 3276800 B
    float*    gx    = (float*)(wsb + 3473408);      // 30720000 B
    _Float16* emb16 = (_Float16*)(wsb + 3473408);   // 12.8 MB, aliases gx (dead before k2)
    float*    pool  = (float*)(wsb);                // aliases wl/k2b: k3 runs after k1/k2
    float*    out   = (float*)d_out;

    // emb conversion blocks: ceil(6,400,000 / 8192) = 782
    k0_prep<<<11 + 782, 256, 0, stream>>>(w_lin, w_ih_f, w_ih_b, emb, wl, k2b, emb16);
    k1_mfma<<<NTREE / 2, 512, 0, stream>>>(tok, emb16, wl, b_lin, thi);
    k2_mfma<<<(NTREE / 32) * 10, 256, 0, stream>>>(thi, k2b, b_ih_f, b_ih_b, gx);
    k3_gru <<<2 * BB, 256, 0, stream>>>(gx, w_hh_f, b_hh_f, w_hh_b, b_hh_b, pool);
    k4_fc  <<<BB, 256, 0, stream>>>(pool, fc_w, fc_b, out);
}

// Round 12
// 247.604 us; speedup vs baseline: 1.0413x; 1.0215x over previous
//
#include <hip/hip_runtime.h>
#include <hip/hip_bf16.h>
#include <math.h>

// Problem dims (fixed by reference)
#define BB 64
#define SS 200
#define TT 32
#define EE 128
#define CC 128
#define HH 100
#define G3 300           // 3*H
#define OUTD 104
#define NTREE (BB*SS)    // 12800
#define EMB_N (50000 * EE)   // 6,400,000 elements

typedef __attribute__((ext_vector_type(4))) float f32x4;
typedef _Float16 f16x8 __attribute__((ext_vector_type(8)));

__device__ inline float fast_sigmoid(float x) {
    return __builtin_amdgcn_rcpf(1.f + __builtin_amdgcn_exp2f(-1.4426950408889634f * x));
}
__device__ inline float fast_tanh(float x) {
    return 1.f - 2.f * __builtin_amdgcn_rcpf(1.f + __builtin_amdgcn_exp2f(2.8853900817779268f * x));
}
__device__ inline unsigned pack2f16(float a, float b) {
    union { _Float16 h[2]; unsigned u; } x;
    x.h[0] = (_Float16)a; x.h[1] = (_Float16)b;
    return x.u;
}
__device__ inline unsigned f2u(float v) { union { float f; unsigned u; } x; x.f = v; return x.u; }
__device__ inline float u2f(unsigned v) { union { unsigned u; float f; } x; x.u = v; return x.f; }
// subtree size of node p in the 32-node complete binary tree
__device__ inline float subtree_cnt(int p) {
    return (p == 0) ? 32.f : (p == 1) ? 16.f : (p == 2) ? 15.f :
           (p == 3) ? 8.f  : (p <= 6) ? 7.f  : (p == 7) ? 4.f  :
           (p <= 14) ? 3.f : (p == 15) ? 2.f : 1.f;
}

// LDS-only barrier: waits ds-ops (lgkmcnt) but does NOT drain vmcnt, so in-flight
// global prefetch loads stay outstanding across the barrier (waited at use).
#define BAR() asm volatile("s_waitcnt lgkmcnt(0)\n\ts_barrier" ::: "memory")

// Workspace layout (bytes):
//   wl    @ 0        : 32768    (k1 W_lin fragment image, fp16)
//   k2b   @ 32768    : 163840   (k2 W_ih fragment image, fp16)
//   lf    @ 196608   : 2048     (k1 L-matrix fragment image, fp16)
//   thi   @ 198656   : 3276800  (tree_vec, fp16)
//   gx    @ 3475456  : 30720000 (fp32) -- ALSO holds emb16 (12.8 MB) during k0/k1;
//                                          k2 overwrites after k1 is done (stream order).
//   pool  @ 0        : 51200    -- aliases wl/k2b; k3 writes AFTER k1/k2 read them.

// ---------------- K0: weight/L fragment images + fp16 embedding table (idempotent)
__global__ __launch_bounds__(256) void k0_prep(const float* __restrict__ w_lin,
                                               const float* __restrict__ w_ih_f,
                                               const float* __restrict__ w_ih_b,
                                               const float* __restrict__ emb,
                                               _Float16* __restrict__ wl,
                                               _Float16* __restrict__ k2b,
                                               _Float16* __restrict__ lf,
                                               _Float16* __restrict__ emb16) {
    const int tid  = threadIdx.x;
    const int wave = tid >> 6;
    const int lane = tid & 63;
    const int r = lane & 15;
    const int q = lane >> 4;
    if (blockIdx.x == 0) {
        // k1 image: flat idx (w8 = wave*2+nt, kt, lane) -> W_lin[n=w8*16+r][k=kt*32+q*8 ..+8]
#pragma unroll
        for (int nt = 0; nt < 2; ++nt)
#pragma unroll
            for (int kt = 0; kt < 4; ++kt) {
                const int n = wave * 32 + nt * 16 + r;
                const float* src = w_lin + (long)n * EE + kt * 32 + q * 8;
                f16x8 f;
#pragma unroll
                for (int e = 0; e < 8; ++e) f[e] = (_Float16)src[e];
                *(f16x8*)&wl[(size_t)((((wave * 2 + nt) * 4 + kt) * 64) + lane) * 8] = f;
            }
        // L-matrix A-fragments (wave 0 only): L[p][n] = (n in subtree(p))
        if (wave == 0) {
#pragma unroll
            for (int mt2 = 0; mt2 < 2; ++mt2) {
                const int p = mt2 * 16 + r;
                f16x8 f;
#pragma unroll
                for (int e = 0; e < 8; ++e) {
                    int x = q * 8 + e;
                    while (x > p) x = (x - 1) >> 1;
                    f[e] = (_Float16)((x == p) ? 1.f : 0.f);
                }
                *(f16x8*)&lf[(size_t)(mt2 * 64 + lane) * 8] = f;
            }
        }
    } else if (blockIdx.x <= 10) {
        // k2 image: nb, wave w, lane(r,q), kt -> W_ih[padded n = nb*64+w*16+r][k=kt*32+q*8]
        const int nb = blockIdx.x - 1;           // 0..9
        const int n = nb * 64 + wave * 16 + r;
        const int dir = (n >= 320) ? 1 : 0;
        const int j = n - dir * 320;
        const int jj = (j < G3) ? j : 0;         // pad rows clamped (results discarded)
        const float* w = dir ? w_ih_b : w_ih_f;
#pragma unroll
        for (int kt = 0; kt < 4; ++kt) {
            const float* src = w + (long)jj * EE + kt * 32 + q * 8;
            f16x8 f;
#pragma unroll
            for (int e = 0; e < 8; ++e) f[e] = (_Float16)src[e];
            *(f16x8*)&k2b[(size_t)((((nb * 4 + wave) * 4 + kt) * 64) + lane) * 8] = f;
        }
    } else {
        // fp16 embedding table: blocks 11.. convert 8192 elements each (streaming)
        const long base = (long)(blockIdx.x - 11) * 8192;
#pragma unroll
        for (int i = 0; i < 4; ++i) {
            const long off = base + i * 2048 + tid * 8;
            if (off < EMB_N) {
                const float4 e0 = ((const float4*)(emb + off))[0];
                const float4 e1 = ((const float4*)(emb + off))[1];
                f16x8 v;
                v[0] = (_Float16)e0.x; v[1] = (_Float16)e0.y; v[2] = (_Float16)e0.z; v[3] = (_Float16)e0.w;
                v[4] = (_Float16)e1.x; v[5] = (_Float16)e1.y; v[6] = (_Float16)e1.z; v[7] = (_Float16)e1.w;
                *(f16x8*)&emb16[off] = v;
            }
        }
    }
}

// ---------------- K1 v4: 4 trees/block (3200 blocks). fp16-gather -> MFMA1 (c = W.e)
// -> wave-local bpermute redistribution -> MFMA2 (h = L.c) -> max + shfl -> store.
#define K1_TPB 4
#define K1_ROWS (K1_TPB * TT)    // 128
#define LDA 136                  // fp16/row: 128 + 8 pad
__global__ __launch_bounds__(512, 4) void k1_mfma(const int* __restrict__ tok,
                                                  const _Float16* __restrict__ emb16,
                                                  const _Float16* __restrict__ wl,
                                                  const _Float16* __restrict__ lf,
                                                  const float* __restrict__ b_lin,
                                                  _Float16* __restrict__ thi) {
    __shared__ __align__(16) _Float16 A_sh[K1_ROWS * LDA];   // 34816 B
    __shared__ int tok_sh[K1_ROWS];

    const int tid  = threadIdx.x;
    const int wave = tid >> 6;      // 0..7, owns cols [16w, 16w+16)
    const int lane = tid & 63;
    const int r = lane & 15;
    const int q = lane >> 4;

    // ---- B fragments (W_lin) + L fragments from prebuilt images (coalesced 16B loads)
    f16x8 bfrag[4];
#pragma unroll
    for (int kt = 0; kt < 4; ++kt)
        bfrag[kt] = *(const f16x8*)&wl[(size_t)(((wave * 4 + kt) * 64) + lane) * 8];
    f16x8 l2f[2];
#pragma unroll
    for (int mt2 = 0; mt2 < 2; ++mt2)
        l2f[mt2] = *(const f16x8*)&lf[(size_t)(mt2 * 64 + lane) * 8];
    const float bias = b_lin[wave * 16 + r];

    const int tree0 = blockIdx.x * K1_TPB;
    if (tid < K1_ROWS) tok_sh[tid] = tok[tree0 * TT + tid];
    __syncthreads();

    // ---- gather fp16 embeddings -> LDS (copy-only; 256 B/row, coalesced per row)
#pragma unroll
    for (int i = 0; i < 4; ++i) {
        const int idx = tid + i * 512;          // 0..2047
        const int row = idx >> 4;               // node row 0..127
        const int p4  = idx & 15;               // 16B chunk
        f16x8 v = *(const f16x8*)&emb16[(size_t)tok_sh[row] * EE + p4 * 8];
        *(f16x8*)&A_sh[row * LDA + p4 * 8] = v;
    }
    __syncthreads();   // only barrier in k1

    // ---- MFMA1: C1[128 nodes][16 cols] per wave; pack each m-tile to fp16 pairs
    unsigned pk[8][2];    // pk[mt][pair]: pair0 = regs(0,1), pair1 = regs(2,3)
#pragma unroll
    for (int mt = 0; mt < 8; ++mt) {
        const int m = mt * 16 + r;
        f32x4 acc = (f32x4)(0.f);
#pragma unroll
        for (int kt = 0; kt < 4; ++kt) {
            f16x8 af = *(const f16x8*)&A_sh[m * LDA + kt * 32 + q * 8];
            acc = __builtin_amdgcn_mfma_f32_16x16x32_f16(af, bfrag[kt], acc, 0, 0, 0);
        }
        pk[mt][0] = pack2f16(acc[0], acc[1]);
        pk[mt][1] = pack2f16(acc[2], acc[3]);
    }

    // ---- per tree: wave-local bpermute (both-tile fetch + dest-side select; the
    // bpermute src operand is evaluated on the SOURCE lane) -> MFMA2 -> max epilogue
    const int l0 = (r + 16 * ((2 * q) & 3)) << 2;
    const int l1 = (r + 16 * ((2 * q + 1) & 3)) << 2;
    const bool hi = (q >> 1) != 0;
#pragma unroll
    for (int t = 0; t < K1_TPB; ++t) {
        const unsigned x0 = __builtin_amdgcn_ds_bpermute(l0, (int)pk[2 * t][0]);
        const unsigned y0 = __builtin_amdgcn_ds_bpermute(l0, (int)pk[2 * t + 1][0]);
        const unsigned x1 = __builtin_amdgcn_ds_bpermute(l0, (int)pk[2 * t][1]);
        const unsigned y1 = __builtin_amdgcn_ds_bpermute(l0, (int)pk[2 * t + 1][1]);
        const unsigned x2 = __builtin_amdgcn_ds_bpermute(l1, (int)pk[2 * t][0]);
        const unsigned y2 = __builtin_amdgcn_ds_bpermute(l1, (int)pk[2 * t + 1][0]);
        const unsigned x3 = __builtin_amdgcn_ds_bpermute(l1, (int)pk[2 * t][1]);
        const unsigned y3 = __builtin_amdgcn_ds_bpermute(l1, (int)pk[2 * t + 1][1]);
        union { unsigned u[4]; f16x8 v; } b2;
        b2.u[0] = hi ? y0 : x0;
        b2.u[1] = hi ? y1 : x1;
        b2.u[2] = hi ? y2 : x2;
        b2.u[3] = hi ? y3 : x3;

        float mx = -1e30f;
#pragma unroll
        for (int mt2 = 0; mt2 < 2; ++mt2) {
            f32x4 a2 = __builtin_amdgcn_mfma_f32_16x16x32_f16(l2f[mt2], b2.v, (f32x4)(0.f), 0, 0, 0);
#pragma unroll
            for (int reg = 0; reg < 4; ++reg) {
                const int p = mt2 * 16 + q * 4 + reg;       // h(p) = C2 + cnt(p)*bias
                mx = fmaxf(mx, a2[reg] + subtree_cnt(p) * bias);
            }
        }
        mx = fmaxf(mx, __shfl_xor(mx, 16, 64));
        mx = fmaxf(mx, __shfl_xor(mx, 32, 64));
        if (q == 0)
            thi[(size_t)(tree0 + t) * CC + wave * 16 + r] = (_Float16)mx;
    }
}

// ---------------- K2 v2 (fp16 MFMA, 128-row M-tiles): gx[dir][m=b*S+s][300] = X @ W_ih^T + b_ih
__global__ __launch_bounds__(256, 4) void k2_mfma(const _Float16* __restrict__ thi,
                                                  const _Float16* __restrict__ k2b,
                                                  const float* __restrict__ b_ih_f,
                                                  const float* __restrict__ b_ih_b,
                                                  float* __restrict__ gx) {
    __shared__ __align__(16) _Float16 Ah[128 * LDA];   // 34816 B

    const int tid  = threadIdx.x;
    const int wave = tid >> 6;
    const int lane = tid & 63;
    const int r = lane & 15;
    const int q = lane >> 4;

    const int nb = blockIdx.x % 10;
    const int mb = blockIdx.x / 10;
    const int m0 = mb * 128;
    const int n0 = nb * 64;

    // stage A: 128 rows x 16 chunks = 2048 f16x8; 8 per thread (copy-only)
#pragma unroll
    for (int i = 0; i < 8; ++i) {
        const int idx = tid + i * 256;
        const int row = idx >> 4;
        const int p   = idx & 15;
        f16x8 v = *(const f16x8*)&thi[(size_t)(m0 + row) * CC + p * 8];
        *(f16x8*)&Ah[row * LDA + p * 8] = v;
    }
    // B fragments: 4 coalesced 16B loads from prebuilt image
    f16x8 bh[4];
#pragma unroll
    for (int kt = 0; kt < 4; ++kt)
        bh[kt] = *(const f16x8*)&k2b[(size_t)((((nb * 4 + wave) * 4 + kt) * 64) + lane) * 8];
    __syncthreads();

    const int ng  = n0 + wave * 16 + r;
    const int dir = (ng >= 320) ? 1 : 0;
    const int j   = ng - dir * 320;
    const bool valid = (j < G3);
    const float bias = valid ? (dir ? b_ih_b[j] : b_ih_f[j]) : 0.f;
    float* gxd = gx + (long)dir * NTREE * G3;

#pragma unroll
    for (int mt = 0; mt < 8; ++mt) {
        const int m = mt * 16 + r;
        f32x4 acc = (f32x4)(0.f);
#pragma unroll
        for (int kt = 0; kt < 4; ++kt) {
            f16x8 a = *(const f16x8*)&Ah[m * LDA + kt * 32 + q * 8];
            acc = __builtin_amdgcn_mfma_f32_16x16x32_f16(a, bh[kt], acc, 0, 0, 0);
        }
        if (valid) {
#pragma unroll
            for (int reg = 0; reg < 4; ++reg) {
                const int mm = m0 + mt * 16 + q * 4 + reg;
                gxd[(long)mm * G3 + j] = acc[reg] + bias;
            }
        }
    }
}

// ---------------- K3 v6 (unchanged, measured 95.6 us): 1 chain/block, fp16 MFMA matvec,
// bpermute gate redistribution, one lgkm-only barrier/step, h double-buffered.
__global__ __launch_bounds__(256, 1) void k3_gru(const float* __restrict__ gx,
                                                 const float* __restrict__ w_hh_f,
                                                 const float* __restrict__ b_hh_f,
                                                 const float* __restrict__ w_hh_b,
                                                 const float* __restrict__ b_hh_b,
                                                 float* __restrict__ pool) {
    const int bid = blockIdx.x;   // 0..127
    const int dir = bid & 1;
    const int b = bid >> 1;
    const float* w_hh = dir ? w_hh_b : w_hh_f;
    const float* b_hh = dir ? b_hh_b : b_hh_f;

    __shared__ __align__(16) _Float16 h_sh[2][128];   // double-buffered h (k-pad 0)

    const int tid  = threadIdx.x;
    const int wave = tid >> 6;
    const int lane = tid & 63;
    const int r = lane & 15;
    const int q = lane >> 4;

    f16x8 bf[5][4];
#pragma unroll
    for (int i = 0; i < 5; ++i) {
        const int l = i * 16 + r;
        const int gate = l / 25;
        const int ch   = l - gate * 25;
        const bool nv  = (l < 75);
        const int row  = gate * HH + wave * 25 + ch;
#pragma unroll
        for (int kt = 0; kt < 4; ++kt) {
            f16x8 f;
#pragma unroll
            for (int e = 0; e < 8; ++e) {
                const int k = kt * 32 + q * 8 + e;
                f[e] = (_Float16)((nv && k < HH) ? w_hh[row * HH + k] : 0.f);
            }
            bf[i][kt] = f;
        }
    }

    const int m = lane;              // activation lane: m<25 owns channel c = 25w+m
    const int c = wave * 25 + m;
    const bool act = (m < 25);
    float br = 0.f, bz = 0.f, bn = 0.f;
    if (act) { br = b_hh[c]; bz = b_hh[HH + c]; bn = b_hh[2 * HH + c]; }

    if (tid < 128) { h_sh[0][tid] = (_Float16)0.f; h_sh[1][tid] = (_Float16)0.f; }

    const float* gxd = gx + (long)dir * NTREE * G3;
    const int sstep = dir ? -1 : 1;
    int s = dir ? (SS - 1) : 0;
    float xr = 0.f, xz = 0.f, xn = 0.f;
    if (act) {
        const float* row0 = gxd + ((long)b * SS + s) * G3;
        xr = row0[c]; xz = row0[HH + c]; xn = row0[2 * HH + c];
    }
    float hj = 0.f, hmax = -1e30f;
    const int lz = ((25 + m) & 15) << 2;
    const int ln = ((50 + m) & 15) << 2;
    __syncthreads();

    for (int t = 0; t < SS; ++t) {
        const int p = t & 1;
        const int s_n = s + sstep;
        float xrn = 0.f, xzn = 0.f, xnn = 0.f;
        if (act && t < SS - 1) {
            const float* row0 = gxd + ((long)b * SS + s_n) * G3;
            xrn = row0[c]; xzn = row0[HH + c]; xnn = row0[2 * HH + c];
        }

        f16x8 a[4];
#pragma unroll
        for (int kt = 0; kt < 4; ++kt)
            a[kt] = *(const f16x8*)&h_sh[p][kt * 32 + q * 8];   // broadcast b128
        float g[5];
#pragma unroll
        for (int i = 0; i < 5; ++i) {
            f32x4 a0 = __builtin_amdgcn_mfma_f32_16x16x32_f16(a[0], bf[i][0], (f32x4)(0.f), 0, 0, 0);
            a0       = __builtin_amdgcn_mfma_f32_16x16x32_f16(a[1], bf[i][1], a0, 0, 0, 0);
            f32x4 a1 = __builtin_amdgcn_mfma_f32_16x16x32_f16(a[2], bf[i][2], (f32x4)(0.f), 0, 0, 0);
            a1       = __builtin_amdgcn_mfma_f32_16x16x32_f16(a[3], bf[i][3], a1, 0, 0, 0);
            g[i] = a0[0] + a1[0];
        }

        const unsigned bz1 = __builtin_amdgcn_ds_bpermute(lz, (int)f2u(g[1]));
        const unsigned bz2 = __builtin_amdgcn_ds_bpermute(lz, (int)f2u(g[2]));
        const unsigned bz3 = __builtin_amdgcn_ds_bpermute(lz, (int)f2u(g[3]));
        const unsigned bn3 = __builtin_amdgcn_ds_bpermute(ln, (int)f2u(g[3]));
        const unsigned bn4 = __builtin_amdgcn_ds_bpermute(ln, (int)f2u(g[4]));

        if (act) {
            const float ghr = (m < 16) ? g[0] : g[1];
            const float ghz = (m < 7) ? u2f(bz1) : (m < 23) ? u2f(bz2) : u2f(bz3);
            const float ghn = (m < 14) ? u2f(bn3) : u2f(bn4);
            const float rg = fast_sigmoid(xr + ghr + br);
            const float zg = fast_sigmoid(xz + ghz + bz);
            const float ng = fast_tanh(xn + rg * (ghn + bn));
            hj = (1.f - zg) * ng + zg * hj;
            hmax = fmaxf(hmax, hj);
            h_sh[1 - p][c] = (_Float16)hj;
            xr = xrn; xz = xzn; xn = xnn;
        }
        BAR();
        s = s_n;
    }
    if (act) pool[(long)b * (2 * HH) + dir * HH + c] = hmax;
}

// ---------------- K4: out[b][o] = fc_b[o] + pool[b,:] . fc_w[o,:]
__global__ __launch_bounds__(256) void k4_fc(const float* __restrict__ pool,
                                             const float* __restrict__ fc_w,
                                             const float* __restrict__ fc_b,
                                             float* __restrict__ out) {
    const int b = blockIdx.x;
    __shared__ __align__(16) float p_sh[2 * HH];
    const int t = threadIdx.x;
    if (t < 2 * HH) p_sh[t] = pool[(long)b * (2 * HH) + t];
    __syncthreads();
    if (t < OUTD) {
        const float4* wr4 = (const float4*)(fc_w + (long)t * (2 * HH));
        const float4* p4 = (const float4*)p_sh;
        float a0 = 0.f, a1 = 0.f;
#pragma unroll
        for (int k = 0; k < 50; k += 2) {
            float4 w0 = wr4[k],   p0 = p4[k];
            float4 w1 = wr4[k+1], p1 = p4[k+1];
            a0 += w0.x*p0.x + w0.y*p0.y + w0.z*p0.z + w0.w*p0.w;
            a1 += w1.x*p1.x + w1.y*p1.y + w1.z*p1.z + w1.w*p1.w;
        }
        out[(long)b * OUTD + t] = fc_b[t] + a0 + a1;
    }
}

extern "C" void kernel_launch(void* const* d_in, const int* in_sizes, int n_in,
                              void* d_out, int out_size, void* d_ws, size_t ws_size,
                              hipStream_t stream) {
    const int*   tok    = (const int*)d_in[0];
    const float* emb    = (const float*)d_in[4];
    const float* w_lin  = (const float*)d_in[5];
    const float* b_lin  = (const float*)d_in[6];
    const float* w_ih_f = (const float*)d_in[7];
    const float* w_hh_f = (const float*)d_in[8];
    const float* b_ih_f = (const float*)d_in[9];
    const float* b_hh_f = (const float*)d_in[10];
    const float* w_ih_b = (const float*)d_in[11];
    const float* w_hh_b = (const float*)d_in[12];
    const float* b_ih_b = (const float*)d_in[13];
    const float* b_hh_b = (const float*)d_in[14];
    const float* fc_w   = (const float*)d_in[15];
    const float* fc_b   = (const float*)d_in[16];

    char* wsb = (char*)d_ws;
    _Float16* wl    = (_Float16*)(wsb);             // 32768 B
    _Float16* k2b   = (_Float16*)(wsb + 32768);     // 163840 B
    _Float16* lf    = (_Float16*)(wsb + 196608);    // 2048 B
    _Float16* thi   = (_Float16*)(wsb + 198656);    // 3276800 B
    float*    gx    = (float*)(wsb + 3475456);      // 30720000 B
    _Float16* emb16 = (_Float16*)(wsb + 3475456);   // 12.8 MB, aliases gx (dead before k2)
    float*    pool  = (float*)(wsb);                // aliases wl/k2b: k3 runs after k1/k2
    float*    out   = (float*)d_out;

    // emb conversion blocks: ceil(6,400,000 / 8192) = 782
    k0_prep<<<11 + 782, 256, 0, stream>>>(w_lin, w_ih_f, w_ih_b, emb, wl, k2b, lf, emb16);
    k1_mfma<<<NTREE / K1_TPB, 512, 0, stream>>>(tok, emb16, wl, lf, b_lin, thi);
    k2_mfma<<<(NTREE / 128) * 10, 256, 0, stream>>>(thi, k2b, b_ih_f, b_ih_b, gx);
    k3_gru <<<2 * BB, 256, 0, stream>>>(gx, w_hh_f, b_hh_f, w_hh_b, b_hh_b, pool);
    k4_fc  <<<BB, 256, 0, stream>>>(pool, fc_w, fc_b, out);
}